// Round 1
// baseline (127.067 us; speedup 1.0000x reference)
//
#include <hip/hip_runtime.h>

// ---------------------------------------------------------------------------
// MixModel: out[n,3j+0] = u[3j]*reg[3j+1]+reg[0] + o1.x + o1.y*ua + o1.z*ub
//           out[n,3j+1] = u[3j+1]*reg[3j+2]+reg[0] + o2.x + o2.y*ua + o2.z*ub
//           out[n,3j+2] = u[3j+2]*reg[3j+3]+reg[0] + o3.x + o3.y*ub
// where (with m = (j+11)%12, p = (j+1)%12):
//   x1 = { u[3m+1], u[3j], u[3j+1] }              -> MLP1 (3->3->6->3)
//   x2 = { u[3j], u[3j+1], u[3p] }                -> MLP2 (3->3->6->3)
//   x3 = { u[3j], u[3j+1], u[3p], u[3p+1] }       -> MLP3 (4->4->6->2)
//   ua = u[3m+2], ub = u[3j+2]
// ---------------------------------------------------------------------------

__device__ __forceinline__ float relu_(float x) { return fmaxf(x, 0.0f); }

// MLP 3 -> 3 -> 6 -> 3 (w0:(3,3), w1:(6,3), w2:(3,6), row-major [out][in])
__device__ __forceinline__ void mlp_a(float x0, float x1, float x2,
                                      const float* __restrict__ w0, const float* __restrict__ b0,
                                      const float* __restrict__ w1, const float* __restrict__ b1,
                                      const float* __restrict__ w2, const float* __restrict__ b2,
                                      float& o0, float& o1, float& o2)
{
    float h0[3];
#pragma unroll
    for (int q = 0; q < 3; ++q)
        h0[q] = relu_(fmaf(x2, w0[q*3+2], fmaf(x1, w0[q*3+1], fmaf(x0, w0[q*3+0], b0[q]))));
    float h1[6];
#pragma unroll
    for (int q = 0; q < 6; ++q)
        h1[q] = relu_(fmaf(h0[2], w1[q*3+2], fmaf(h0[1], w1[q*3+1], fmaf(h0[0], w1[q*3+0], b1[q]))));
    float t[3];
#pragma unroll
    for (int q = 0; q < 3; ++q) {
        float a = b2[q];
#pragma unroll
        for (int i = 0; i < 6; ++i) a = fmaf(h1[i], w2[q*6+i], a);
        t[q] = a;
    }
    o0 = t[0]; o1 = t[1]; o2 = t[2];
}

// MLP 4 -> 4 -> 6 -> 2 (w0:(4,4), w1:(6,4), w2:(2,6))
__device__ __forceinline__ void mlp_b(float x0, float x1, float x2, float x3,
                                      const float* __restrict__ w0, const float* __restrict__ b0,
                                      const float* __restrict__ w1, const float* __restrict__ b1,
                                      const float* __restrict__ w2, const float* __restrict__ b2,
                                      float& o0, float& o1)
{
    float h0[4];
#pragma unroll
    for (int q = 0; q < 4; ++q)
        h0[q] = relu_(fmaf(x3, w0[q*4+3], fmaf(x2, w0[q*4+2], fmaf(x1, w0[q*4+1], fmaf(x0, w0[q*4+0], b0[q])))));
    float h1[6];
#pragma unroll
    for (int q = 0; q < 6; ++q)
        h1[q] = relu_(fmaf(h0[3], w1[q*4+3], fmaf(h0[2], w1[q*4+2], fmaf(h0[1], w1[q*4+1], fmaf(h0[0], w1[q*4+0], b1[q])))));
    float t[2];
#pragma unroll
    for (int q = 0; q < 2; ++q) {
        float a = b2[q];
#pragma unroll
        for (int i = 0; i < 6; ++i) a = fmaf(h1[i], w2[q*6+i], a);
        t[q] = a;
    }
    o0 = t[0]; o1 = t[1];
}

__global__ __launch_bounds__(256) void mixmodel_kernel(
    const float* __restrict__ u, const float* __restrict__ reg,
    const float* __restrict__ w10, const float* __restrict__ b10,
    const float* __restrict__ w11, const float* __restrict__ b11,
    const float* __restrict__ w12, const float* __restrict__ b12,
    const float* __restrict__ w20, const float* __restrict__ b20,
    const float* __restrict__ w21, const float* __restrict__ b21,
    const float* __restrict__ w22, const float* __restrict__ b22,
    const float* __restrict__ w30, const float* __restrict__ b30,
    const float* __restrict__ w31, const float* __restrict__ b31,
    const float* __restrict__ w32, const float* __restrict__ b32,
    float* __restrict__ out, int n)
{
    const int tid = blockIdx.x * blockDim.x + threadIdx.x;
    if (tid >= n) return;

    // ---- load row: 9 x float4 (row stride 144 B, 16B-aligned) ----
    float uu[36];
    const float4* __restrict__ u4 = reinterpret_cast<const float4*>(u + (size_t)tid * 36);
#pragma unroll
    for (int k = 0; k < 9; ++k) {
        float4 v = u4[k];
        uu[4*k+0] = v.x; uu[4*k+1] = v.y; uu[4*k+2] = v.z; uu[4*k+3] = v.w;
    }

    // ---- outreg: o[k] = u[k]*reg[k+1] + reg[0] ----
    float o[36];
    const float r0 = reg[0];
#pragma unroll
    for (int k = 0; k < 36; ++k) o[k] = fmaf(uu[k], reg[k+1], r0);

    // ---- phase 1: MLP1 -> columns 3j ----
#pragma unroll
    for (int j = 0; j < 12; ++j) {
        const int m = (j + 11) % 12;
        float a0, a1, a2;
        mlp_a(uu[3*m+1], uu[3*j], uu[3*j+1], w10, b10, w11, b11, w12, b12, a0, a1, a2);
        const float ua = uu[3*m+2];
        const float ub = uu[3*j+2];
        o[3*j] += fmaf(a2, ub, fmaf(a1, ua, a0));
    }

    // ---- phase 2: MLP2 -> columns 3j+1 ----
#pragma unroll
    for (int j = 0; j < 12; ++j) {
        const int m = (j + 11) % 12;
        const int p = (j + 1) % 12;
        float a0, a1, a2;
        mlp_a(uu[3*j], uu[3*j+1], uu[3*p], w20, b20, w21, b21, w22, b22, a0, a1, a2);
        const float ua = uu[3*m+2];
        const float ub = uu[3*j+2];
        o[3*j+1] += fmaf(a2, ub, fmaf(a1, ua, a0));
    }

    // ---- phase 3: MLP3 -> columns 3j+2 ----
#pragma unroll
    for (int j = 0; j < 12; ++j) {
        const int p = (j + 1) % 12;
        float a0, a1;
        mlp_b(uu[3*j], uu[3*j+1], uu[3*p], uu[3*p+1], w30, b30, w31, b31, w32, b32, a0, a1);
        const float ub = uu[3*j+2];
        o[3*j+2] += fmaf(a1, ub, a0);
    }

    // ---- store: 9 x float4 ----
    float4* o4 = reinterpret_cast<float4*>(out + (size_t)tid * 36);
#pragma unroll
    for (int k = 0; k < 9; ++k)
        o4[k] = make_float4(o[4*k+0], o[4*k+1], o[4*k+2], o[4*k+3]);
}

extern "C" void kernel_launch(void* const* d_in, const int* in_sizes, int n_in,
                              void* d_out, int out_size, void* d_ws, size_t ws_size,
                              hipStream_t stream)
{
    // d_in order: t, u, reg, n1_w0, n1_b0, n1_w1, n1_b1, n1_w2, n1_b2,
    //             n2_w0, n2_b0, n2_w1, n2_b1, n2_w2, n2_b2,
    //             n3_w0, n3_b0, n3_w1, n3_b1, n3_w2, n3_b2
    const float* u   = (const float*)d_in[1];
    const float* reg = (const float*)d_in[2];
    const float* w10 = (const float*)d_in[3];
    const float* b10 = (const float*)d_in[4];
    const float* w11 = (const float*)d_in[5];
    const float* b11 = (const float*)d_in[6];
    const float* w12 = (const float*)d_in[7];
    const float* b12 = (const float*)d_in[8];
    const float* w20 = (const float*)d_in[9];
    const float* b20 = (const float*)d_in[10];
    const float* w21 = (const float*)d_in[11];
    const float* b21 = (const float*)d_in[12];
    const float* w22 = (const float*)d_in[13];
    const float* b22 = (const float*)d_in[14];
    const float* w30 = (const float*)d_in[15];
    const float* b30 = (const float*)d_in[16];
    const float* w31 = (const float*)d_in[17];
    const float* b31 = (const float*)d_in[18];
    const float* w32 = (const float*)d_in[19];
    const float* b32 = (const float*)d_in[20];
    float* out = (float*)d_out;

    const int n = in_sizes[1] / 36;  // 1,000,000 rows
    const int block = 256;
    const int grid = (n + block - 1) / block;

    hipLaunchKernelGGL(mixmodel_kernel, dim3(grid), dim3(block), 0, stream,
                       u, reg, w10, b10, w11, b11, w12, b12,
                       w20, b20, w21, b21, w22, b22,
                       w30, b30, w31, b31, w32, b32, out, n);
}